// Round 6
// baseline (2658.176 us; speedup 1.0000x reference)
//
#include <hip/hip_runtime.h>
#include <stdint.h>

typedef int v4i __attribute__((ext_vector_type(4)));

static constexpr int Mdim = 4096;
static constexpr int Kdim = 4096;   // IN
static constexpr int Ndim = 11008;  // OUT

#define BM 256
#define BN 256
#define BK 64
#define NT (Kdim / BK)  // 64 K-tiles

__device__ __forceinline__ void gload_lds16(const void* gp, void* lp) {
  __builtin_amdgcn_global_load_lds((const __attribute__((address_space(1))) void*)gp,
                                   (__attribute__((address_space(3))) void*)lp,
                                   16, 0, 0);
}

// ---------------- activation static quant + row sums ----------------
__global__ void k_quant(const float* __restrict__ x, const float* __restrict__ clampv,
                        signed char* __restrict__ qa, int* __restrict__ rowsum) {
  const int row = blockIdx.x;
  const int t = threadIdx.x;
  const float cv = clampv[0];
  const float a_scale = cv / 127.0f;
  const float4* xp = (const float4*)(x + (size_t)row * Kdim) + t * 4;
  int s = 0;
  int w[4];
#pragma unroll
  for (int i = 0; i < 4; ++i) {
    float4 f = xp[i];
    float q0 = fminf(fmaxf(rintf(fminf(fmaxf(f.x, -cv), cv) / a_scale), -127.f), 127.f);
    float q1 = fminf(fmaxf(rintf(fminf(fmaxf(f.y, -cv), cv) / a_scale), -127.f), 127.f);
    float q2 = fminf(fmaxf(rintf(fminf(fmaxf(f.z, -cv), cv) / a_scale), -127.f), 127.f);
    float q3 = fminf(fmaxf(rintf(fminf(fmaxf(f.w, -cv), cv) / a_scale), -127.f), 127.f);
    int i0 = (int)q0, i1 = (int)q1, i2 = (int)q2, i3 = (int)q3;
    s += i0 + i1 + i2 + i3;
    w[i] = (i0 & 255) | ((i1 & 255) << 8) | ((i2 & 255) << 16) | ((i3 & 255) << 24);
  }
  ((int4*)(qa + (size_t)row * Kdim))[t] = make_int4(w[0], w[1], w[2], w[3]);
#pragma unroll
  for (int off = 32; off > 0; off >>= 1) s += __shfl_down(s, off, 64);
  __shared__ int red[4];
  if ((t & 63) == 0) red[t >> 6] = s;
  __syncthreads();
  if (t == 0) rowsum[row] = red[0] + red[1] + red[2] + red[3];
}

// ---------------- int4 unpack: [N][K/2] int32 -> [N][K] int8 ----------------
__global__ void k_unpack(const int4* __restrict__ qw, uint2* __restrict__ wb) {
  const int idx = blockIdx.x * 256 + threadIdx.x;
  int4 q = qw[idx];
  uint2 r;
  r.x = (unsigned)(((q.x >> 4) & 15) | ((q.x & 15) << 8) |
                   (((q.y >> 4) & 15) << 16) | ((q.y & 15) << 24));
  r.y = (unsigned)(((q.z >> 4) & 15) | ((q.z & 15) << 8) |
                   (((q.w >> 4) & 15) << 16) | ((q.w & 15) << 24));
  wb[idx] = r;
}

// ---------------- int8 GEMM: 256x256 tile, BK=64, 8 waves, 2 blocks/CU -------
// R6: halve BK so LDS = 64KB/block -> 2 resident blocks/CU. Cross-BLOCK overlap
// hides the LDS-read phase under the other block's MFMA phase (R1/R3/R4/R5
// showed intra-block schemes can't: the tile barrier re-locks wave phases).
// 64B rows = 4 x 16B chunks; swizzle: stored slot s holds global chunk
// s ^ ((row>>1)&3)  (bank = 16*row + 4*chunk mod 32: parity + XOR cover all
// 8 bank-quads -> 2-way max = free). All row offsets (wm, i*16, 128*i staging)
// are 0 mod swizzle period. Free-drift schedule, one barrier + vmcnt(0)/tile.
__global__ __launch_bounds__(512, 4) void k_gemm(
    const signed char* __restrict__ A, const signed char* __restrict__ B,
    const float* __restrict__ scales, const int* __restrict__ qzeros,
    const float* __restrict__ bias, const float* __restrict__ clampv,
    const int* __restrict__ rowsum, float* __restrict__ out) {
  __shared__ signed char lds[65536];           // A: 2x16KB, B: 2x16KB
  signed char* As = lds;
  signed char* Bs = lds + 32768;

  const int t = threadIdx.x;
  const int lane = t & 63;
  const int wave = t >> 6;                      // 0..7 (2M x 4N)
  const int wm = (wave >> 2) * 128;
  const int wn = (wave & 3) * 64;

  // XCD-aware bijective swizzle: 688 blocks = 8 XCDs * 86
  const int bid = blockIdx.x;
  const int swz = (bid & 7) * 86 + (bid >> 3);
  const int mt = swz / 43;                      // consecutive swz share A panel
  const int nt = swz - mt * 43;
  const int m0 = mt * BM;
  const int n0 = nt * BN;

  // staging: thread t covers row srow = t>>2 (+128 per issue), LDS slot t&3.
  // pre-swizzled global chunk keeps LDS dest linear (gload_lds rule).
  const int srow = t >> 2;                      // 0..127
  const int sch = (t & 3) ^ ((srow >> 1) & 3);
  const signed char* gA = A + (size_t)(m0 + srow) * Kdim + sch * 16;
  const signed char* gB = B + (size_t)(n0 + srow) * Kdim + sch * 16;
  const int sdst = t * 16;

#define STAGE_A(buf, k0)                                               \
  {                                                                    \
    _Pragma("unroll") for (int i = 0; i < 2; ++i)                      \
        gload_lds16(gA + (size_t)(i * 128) * Kdim + (k0),              \
                    As + (buf) * 16384 + i * 8192 + sdst);             \
  }
#define STAGE_B(buf, k0)                                               \
  {                                                                    \
    _Pragma("unroll") for (int i = 0; i < 2; ++i)                      \
        gload_lds16(gB + (size_t)(i * 128) * Kdim + (k0),              \
                    Bs + (buf) * 16384 + i * 8192 + sdst);             \
  }

  // fragment addressing: col = lane&15, k-chunk q16 = lane>>4 (K=64 = one row),
  // stored slot = q16 ^ ((row>>1)&3); row = ...+col with offsets 0 mod period.
  const int col = lane & 15;
  const int q16 = lane >> 4;
  const int pos = (q16 ^ ((col >> 1) & 3)) * 16;
  const int aoff = (wm + col) * BK + pos;
  const int boff = (wn + col) * BK + pos;

  v4i acc[8][4] = {};
  v4i a[8], b[4];

#define LOADK()                                                             \
  {                                                                         \
    _Pragma("unroll") for (int j = 0; j < 4; ++j)                           \
        b[j] = *(const v4i*)(Bc + j * 1024 + boff);                         \
    _Pragma("unroll") for (int i = 0; i < 8; ++i)                           \
        a[i] = *(const v4i*)(Ac + i * 1024 + aoff);                         \
  }
#define MFMAK()                                                             \
  {                                                                         \
    __builtin_amdgcn_s_setprio(1);                                          \
    _Pragma("unroll") for (int i = 0; i < 8; ++i)                           \
        _Pragma("unroll") for (int j = 0; j < 4; ++j)                       \
            acc[i][j] = __builtin_amdgcn_mfma_i32_16x16x64_i8(              \
                a[i], b[j], acc[i][j], 0, 0, 0);                            \
    __builtin_amdgcn_s_setprio(0);                                          \
  }

  // prologue: stage tile 0 into buffer 0, publish
  STAGE_A(0, 0);
  STAGE_B(0, 0);
  asm volatile("s_waitcnt vmcnt(0)" ::: "memory");
  __builtin_amdgcn_s_barrier();

  int cur = 0;
  for (int ti = 0; ti < NT - 1; ++ti) {
    const int nk = (ti + 1) * BK;
    const signed char* Ac = As + cur * 16384;
    const signed char* Bc = Bs + cur * 16384;

    // issue next-tile staging first (max time in flight before the drain)
    STAGE_A(cur ^ 1, nk);
    STAGE_B(cur ^ 1, nk);

    LOADK();
    MFMAK();

    // drain our stage loads, then flip
    asm volatile("s_waitcnt vmcnt(0)" ::: "memory");
    __builtin_amdgcn_s_barrier();
    cur ^= 1;
  }
  // last tile: no prefetch, no barrier needed after
  {
    const signed char* Ac = As + cur * 16384;
    const signed char* Bc = Bs + cur * 16384;
    LOADK();
    MFMAK();
  }
#undef STAGE_A
#undef STAGE_B
#undef LOADK
#undef MFMAK

  // epilogue: out = a_scale*scale[n]*(acc - qz[n]*rowsum[m]) + bias[n]
  const float a_scale = clampv[0] / 127.0f;
  const int rq = q16 * 4;
  int rs[8][4];
#pragma unroll
  for (int i = 0; i < 8; ++i)
#pragma unroll
    for (int r = 0; r < 4; ++r)
      rs[i][r] = rowsum[m0 + wm + i * 16 + rq + r];
#pragma unroll
  for (int j = 0; j < 4; ++j) {
    const int n = n0 + wn + j * 16 + col;
    const float sn = scales[n] * a_scale;
    const int zn = qzeros[n];
    const float bn = bias[n];
#pragma unroll
    for (int i = 0; i < 8; ++i) {
      const int mb = m0 + wm + i * 16 + rq;
#pragma unroll
      for (int r = 0; r < 4; ++r) {
        const int iv = acc[i][j][r] - zn * rs[i][r];
        out[(size_t)(mb + r) * Ndim + n] = (float)iv * sn + bn;
      }
    }
  }
}

extern "C" void kernel_launch(void* const* d_in, const int* in_sizes, int n_in,
                              void* d_out, int out_size, void* d_ws, size_t ws_size,
                              hipStream_t stream) {
  const float* x  = (const float*)d_in[0];
  const int* qw   = (const int*)d_in[1];
  const int* qz   = (const int*)d_in[2];
  const float* sc = (const float*)d_in[3];
  const float* bi = (const float*)d_in[4];
  const float* cv = (const float*)d_in[5];
  float* out = (float*)d_out;

  signed char* qa = (signed char*)d_ws;
  signed char* wb = qa + (size_t)Mdim * Kdim;
  int* rowsum = (int*)(wb + (size_t)Ndim * Kdim);

  k_quant<<<Mdim, 256, 0, stream>>>(x, cv, qa, rowsum);
  k_unpack<<<(Ndim * (Kdim / 2) / 4) / 256, 256, 0, stream>>>((const int4*)qw, (uint2*)wb);
  k_gemm<<<dim3((Mdim / BM) * (Ndim / BN)), 512, 0, stream>>>(qa, wb, sc, qz, bi, cv, rowsum, out);
}

// Round 7
// 587.950 us; speedup vs baseline: 4.5211x; 4.5211x over previous
//
#include <hip/hip_runtime.h>
#include <stdint.h>

typedef int v4i __attribute__((ext_vector_type(4)));

static constexpr int Mdim = 4096;
static constexpr int Kdim = 4096;   // IN
static constexpr int Ndim = 11008;  // OUT

#define BM 256
#define BN 256
#define BK 128
#define NT (Kdim / BK)  // 32 K-tiles

__device__ __forceinline__ void gload_lds16(const void* gp, void* lp) {
  __builtin_amdgcn_global_load_lds((const __attribute__((address_space(1))) void*)gp,
                                   (__attribute__((address_space(3))) void*)lp,
                                   16, 0, 0);
}

// ---------------- activation static quant + row sums ----------------
__global__ void k_quant(const float* __restrict__ x, const float* __restrict__ clampv,
                        signed char* __restrict__ qa, int* __restrict__ rowsum) {
  const int row = blockIdx.x;
  const int t = threadIdx.x;
  const float cv = clampv[0];
  const float a_scale = cv / 127.0f;
  const float4* xp = (const float4*)(x + (size_t)row * Kdim) + t * 4;
  int s = 0;
  int w[4];
#pragma unroll
  for (int i = 0; i < 4; ++i) {
    float4 f = xp[i];
    float q0 = fminf(fmaxf(rintf(fminf(fmaxf(f.x, -cv), cv) / a_scale), -127.f), 127.f);
    float q1 = fminf(fmaxf(rintf(fminf(fmaxf(f.y, -cv), cv) / a_scale), -127.f), 127.f);
    float q2 = fminf(fmaxf(rintf(fminf(fmaxf(f.z, -cv), cv) / a_scale), -127.f), 127.f);
    float q3 = fminf(fmaxf(rintf(fminf(fmaxf(f.w, -cv), cv) / a_scale), -127.f), 127.f);
    int i0 = (int)q0, i1 = (int)q1, i2 = (int)q2, i3 = (int)q3;
    s += i0 + i1 + i2 + i3;
    w[i] = (i0 & 255) | ((i1 & 255) << 8) | ((i2 & 255) << 16) | ((i3 & 255) << 24);
  }
  ((int4*)(qa + (size_t)row * Kdim))[t] = make_int4(w[0], w[1], w[2], w[3]);
#pragma unroll
  for (int off = 32; off > 0; off >>= 1) s += __shfl_down(s, off, 64);
  __shared__ int red[4];
  if ((t & 63) == 0) red[t >> 6] = s;
  __syncthreads();
  if (t == 0) rowsum[row] = red[0] + red[1] + red[2] + red[3];
}

// ---------------- int4 unpack: [N][K/2] int32 -> [N][K] int8 ----------------
__global__ void k_unpack(const int4* __restrict__ qw, uint2* __restrict__ wb) {
  const int idx = blockIdx.x * 256 + threadIdx.x;
  int4 q = qw[idx];
  uint2 r;
  r.x = (unsigned)(((q.x >> 4) & 15) | ((q.x & 15) << 8) |
                   (((q.y >> 4) & 15) << 16) | ((q.y & 15) << 24));
  r.y = (unsigned)(((q.z >> 4) & 15) | ((q.z & 15) << 8) |
                   (((q.w >> 4) & 15) << 16) | ((q.w & 15) << 24));
  wb[idx] = r;
}

// ---------------- int8 GEMM: 256x256 tile, 8 waves, 16x16x64 MFMA ----------------
// R7 = R3 (best verified, 197us) with B moved OFF the LDS pipe:
//   - A: global_load_lds staged, XOR-swizzled (R3-verified, 0 conflicts), 4x reuse.
//   - B: fragments read DIRECTLY from global (L1/L2-resident panel; lanes
//     {c,c+16,c+32,c+48} form contiguous 64B segments -> coalescible).
// LDS pipe work/tile: 192KB->128KB reads, 64KB->32KB writes (now < MFMA time);
// B's ~1200cy moves to the otherwise-idle vmem pipe. LDS = 64KB (A dbuf only).
// Free-drift schedule, one s_barrier + vmcnt(0) per K-tile (R3 safety argument).
__global__ __launch_bounds__(512, 2) void k_gemm(
    const signed char* __restrict__ A, const signed char* __restrict__ B,
    const float* __restrict__ scales, const int* __restrict__ qzeros,
    const float* __restrict__ bias, const float* __restrict__ clampv,
    const int* __restrict__ rowsum, float* __restrict__ out) {
  __shared__ signed char As[65536];            // A: 2 x 32KB double buffer

  const int t = threadIdx.x;
  const int lane = t & 63;
  const int wave = t >> 6;                      // 0..7 (2M x 4N)
  const int wm = (wave >> 2) * 128;
  const int wn = (wave & 3) * 64;

  // XCD-aware bijective swizzle: 688 blocks = 8 XCDs * 86
  const int bid = blockIdx.x;
  const int swz = (bid & 7) * 86 + (bid >> 3);
  const int mt = swz / 43;                      // consecutive swz share A panel
  const int nt = swz - mt * 43;
  const int m0 = mt * BM;
  const int n0 = nt * BN;

  // A staging: thread t covers row srow (+i*64 per issue), LDS chunk t&7.
  // pre-swizzled global source chunk keeps LDS dest linear (gload_lds rule).
  const int srow = t >> 3;                      // 0..63
  const int sch = (t & 7) ^ (srow & 7);
  const signed char* gA = A + (size_t)(m0 + srow) * Kdim + sch * 16;
  const int sdst = t * 16;

#define STAGE_A(buf, k0)                                               \
  {                                                                    \
    _Pragma("unroll") for (int i = 0; i < 4; ++i)                      \
        gload_lds16(gA + (size_t)(i * 64) * Kdim + (k0),               \
                    &As[(buf) * 32768 + i * 8192 + sdst]);             \
  }

  // fragment addressing (16x16 MFMA): col = lane&15, 16B chunk (ks*4 + lane>>4),
  // A stored chunk XOR'd with row&7 == col&7 (wm, i*16 are multiples of 8).
  const int col = lane & 15;
  const int q16 = lane >> 4;
  const int c7 = col & 7;
  int aoff[2];
#pragma unroll
  for (int ks = 0; ks < 2; ++ks)
    aoff[ks] = (wm + col) * BK + (((ks * 4 + q16) ^ c7) * 16);

  // B fragment base: row (n0 + wn + j*16 + col), k-chunk (ks*4+q16)*16 within tile
  const signed char* gBf = B + (size_t)(n0 + wn + col) * Kdim + q16 * 16;

  v4i acc[8][4] = {};
  v4i a[2][8], b[2][4];

  // b first (vmem latency), then a (LDS); MFMAs consume after.
#define LOADB(k0)                                                           \
  {                                                                         \
    _Pragma("unroll") for (int ks = 0; ks < 2; ++ks)                        \
        _Pragma("unroll") for (int j = 0; j < 4; ++j)                       \
            b[ks][j] = *(const v4i*)(gBf + (size_t)(j * 16) * Kdim +        \
                                     (k0) + ks * 64);                       \
  }
#define LOADA(bank, ks_)                                                    \
  {                                                                         \
    _Pragma("unroll") for (int i = 0; i < 8; ++i)                           \
        a[bank][i] = *(const v4i*)(Ac + i * 2048 + aoff[ks_]);              \
  }
#define MFMAK(bank)                                                         \
  {                                                                         \
    __builtin_amdgcn_s_setprio(1);                                          \
    _Pragma("unroll") for (int i = 0; i < 8; ++i)                           \
        _Pragma("unroll") for (int j = 0; j < 4; ++j)                       \
            acc[i][j] = __builtin_amdgcn_mfma_i32_16x16x64_i8(              \
                a[bank][i], b[bank][j], acc[i][j], 0, 0, 0);                \
    __builtin_amdgcn_s_setprio(0);                                          \
  }

  // prologue: stage A tile 0 into buffer 0, publish
  STAGE_A(0, 0);
  asm volatile("s_waitcnt vmcnt(0)" ::: "memory");
  __builtin_amdgcn_s_barrier();

  int cur = 0;
  for (int ti = 0; ti < NT - 1; ++ti) {
    const int k0 = ti * BK;
    const signed char* Ac = &As[cur * 32768];

    // issue next-tile A staging first (max flight before the drain),
    // then this tile's B loads (consumed after the LDS a-reads).
    STAGE_A(cur ^ 1, k0 + BK);
    LOADB(k0);
    LOADA(0, 0);
    LOADA(1, 1);
    MFMAK(0);
    MFMAK(1);

    // stage-A loads issued ~2600cy ago; b loads already consumed by MFMAs.
    asm volatile("s_waitcnt vmcnt(0)" ::: "memory");
    __builtin_amdgcn_s_barrier();
    cur ^= 1;
  }
  // last tile: no prefetch, no barrier needed after
  {
    const int k0 = (NT - 1) * BK;
    const signed char* Ac = &As[cur * 32768];
    LOADB(k0);
    LOADA(0, 0);
    LOADA(1, 1);
    MFMAK(0);
    MFMAK(1);
  }
#undef STAGE_A
#undef LOADB
#undef LOADA
#undef MFMAK

  // epilogue: out = a_scale*scale[n]*(acc - qz[n]*rowsum[m]) + bias[n]
  const float a_scale = clampv[0] / 127.0f;
  const int rq = q16 * 4;
  int rs[8][4];
#pragma unroll
  for (int i = 0; i < 8; ++i)
#pragma unroll
    for (int r = 0; r < 4; ++r)
      rs[i][r] = rowsum[m0 + wm + i * 16 + rq + r];
#pragma unroll
  for (int j = 0; j < 4; ++j) {
    const int n = n0 + wn + j * 16 + col;
    const float sn = scales[n] * a_scale;
    const int zn = qzeros[n];
    const float bn = bias[n];
#pragma unroll
    for (int i = 0; i < 8; ++i) {
      const int mb = m0 + wm + i * 16 + rq;
#pragma unroll
      for (int r = 0; r < 4; ++r) {
        const int iv = acc[i][j][r] - zn * rs[i][r];
        out[(size_t)(mb + r) * Ndim + n] = (float)iv * sn + bn;
      }
    }
  }
}

extern "C" void kernel_launch(void* const* d_in, const int* in_sizes, int n_in,
                              void* d_out, int out_size, void* d_ws, size_t ws_size,
                              hipStream_t stream) {
  const float* x  = (const float*)d_in[0];
  const int* qw   = (const int*)d_in[1];
  const int* qz   = (const int*)d_in[2];
  const float* sc = (const float*)d_in[3];
  const float* bi = (const float*)d_in[4];
  const float* cv = (const float*)d_in[5];
  float* out = (float*)d_out;

  signed char* qa = (signed char*)d_ws;
  signed char* wb = qa + (size_t)Mdim * Kdim;
  int* rowsum = (int*)(wb + (size_t)Ndim * Kdim);

  k_quant<<<Mdim, 256, 0, stream>>>(x, cv, qa, rowsum);
  k_unpack<<<(Ndim * (Kdim / 2) / 4) / 256, 256, 0, stream>>>((const int4*)qw, (uint2*)wb);
  k_gemm<<<dim3((Mdim / BM) * (Ndim / BN)), 512, 0, stream>>>(qa, wb, sc, qz, bi, cv, rowsum, out);
}